// Round 5
// baseline (78.034 us; speedup 1.0000x reference)
//
#include <hip/hip_runtime.h>
#include <hip/hip_bf16.h>

// LinearMinimumBit: y = x @ dequant3bit(W)^T + bias
// x:[64,8192] f32, weight_q3:[4194304,6] int32 (byte values), weight_norm:[4194304] f32,
// bias:[8192] f32 -> out:[64,8192] f32
//
// Barrier-free, LDS-free. Each lane dequantizes exactly the 8 weights its MFMA
// B-fragment needs (3 packed int32s = 12B, dwordx3). KEY (round 5): A and B
// prefetch at EQUAL depth 4 in FIFO issue order -- the single in-order vmcnt
// counter means unequal depths force retiring young HBM loads when consuming
// the shallow stream (rounds 1-4 were pinned at ~800 cy/iter by this).
//
// ws: [0,1MB) x as bf16; [1MB, 1MB+KS*2MB) partials [KS][64][8192] f32

#define BATCH   64
#define IN_F    8192
#define OUT_F   8192

typedef __attribute__((ext_vector_type(8))) short bf16x8;
typedef __attribute__((ext_vector_type(4))) float f32x4;

__device__ __forceinline__ ushort f2bf(float f) {
  union { float f; unsigned u; } a; a.f = f;
  unsigned r = a.u + 0x7fffu + ((a.u >> 16) & 1u);
  return (ushort)(r >> 16);
}

__global__ void __launch_bounds__(256) xcvt_kernel(const float* __restrict__ x,
                                                   ushort* __restrict__ xb) {
  int i = blockIdx.x * 256 + threadIdx.x;
  float4 v = ((const float4*)x)[i];
  ushort4 o;
  o.x = f2bf(v.x); o.y = f2bf(v.y); o.z = f2bf(v.z); o.w = f2bf(v.w);
  ((ushort4*)xb)[i] = o;
}

// 3 byte-values + norm -> 8 bf16 weights (w = v*(2n/7) - n), fragment-ordered
__device__ __forceinline__ bf16x8 dqfrag(int b0, int b1, int b2, float nrm) {
  float c1 = nrm * (2.0f / 7.0f);
  float c0 = nrm;
  int v0 = (b0 >> 5) & 7;
  int v1 = (b0 >> 2) & 7;
  int v2 = ((b0 & 3) << 1) | ((b1 >> 7) & 1);
  int v3 = (b1 >> 4) & 7;
  int v4 = (b1 >> 1) & 7;
  int v5 = ((b1 & 1) << 2) | ((b2 >> 6) & 3);
  int v6 = (b2 >> 3) & 7;
  int v7 = b2 & 7;
  union { __hip_bfloat162 h[4]; bf16x8 v; } r;
  r.h[0] = __float22bfloat162_rn(make_float2(fmaf((float)v0, c1, -c0), fmaf((float)v1, c1, -c0)));
  r.h[1] = __float22bfloat162_rn(make_float2(fmaf((float)v2, c1, -c0), fmaf((float)v3, c1, -c0)));
  r.h[2] = __float22bfloat162_rn(make_float2(fmaf((float)v4, c1, -c0), fmaf((float)v5, c1, -c0)));
  r.h[3] = __float22bfloat162_rn(make_float2(fmaf((float)v6, c1, -c0), fmaf((float)v7, c1, -c0)));
  return r.v;
}

template <int KS>
__global__ void __launch_bounds__(256) gemm3b_kernel(const ushort* __restrict__ xb,
                                                     const int* __restrict__ wq,
                                                     const float* __restrict__ wnorm,
                                                     float* __restrict__ partial) {
  constexpr int K_SLICE = IN_F / KS;
  constexpr int NIT = K_SLICE / 32;   // 32-k per iteration (>= 8)

  const int tid  = threadIdx.x;
  const int lane = tid & 63;
  const int w    = tid >> 6;          // wave w owns cols [nb, nb+32)
  const int l15  = lane & 15;
  const int h    = lane >> 4;         // k-chunk 0..3 within the 32-k step
  const int nb   = blockIdx.x * 128 + w * 32;
  const int s    = blockIdx.y;
  const int kbase = s * K_SLICE;

  const long row0 = nb + l15;
  const int* __restrict__ pq0 = wq + (row0 * 512 + (long)(kbase >> 4) + (h >> 1)) * 6 + (h & 1) * 3;
  const int* __restrict__ pq1 = pq0 + (long)16 * 512 * 6;
  const float* __restrict__ pn0 = wnorm + row0 * 512 + (kbase >> 4) + (h >> 1);
  const float* __restrict__ pn1 = pn0 + 16 * 512;
  const ushort* __restrict__ pa = xb + l15 * IN_F + kbase + h * 8;

  f32x4 acc[2][4];
  #pragma unroll
  for (int n = 0; n < 2; ++n)
    #pragma unroll
    for (int m = 0; m < 4; ++m) acc[n][m] = (f32x4){0.f, 0.f, 0.f, 0.f};

  // 4 pipeline slots, A and B at EQUAL depth (static names only)
  int qa0[3], qb0[3]; float na0, nb0; bf16x8 A00, A01, A02, A03;
  int qa1[3], qb1[3]; float na1, nb1; bf16x8 A10, A11, A12, A13;
  int qa2[3], qb2[3]; float na2, nb2; bf16x8 A20, A21, A22, A23;
  int qa3[3], qb3[3]; float na3, nb3; bf16x8 A30, A31, A32, A33;

#define LOADAB(SL, IT)                                   \
  do {                                                   \
    __builtin_memcpy(qa##SL, pq0 + (IT) * 12, 12);       \
    __builtin_memcpy(qb##SL, pq1 + (IT) * 12, 12);       \
    na##SL = pn0[(IT) * 2];                              \
    nb##SL = pn1[(IT) * 2];                              \
    const ushort* pA_ = pa + (IT) * 32;                  \
    A##SL##0 = *(const bf16x8*)(pA_);                    \
    A##SL##1 = *(const bf16x8*)(pA_ + 16 * IN_F);        \
    A##SL##2 = *(const bf16x8*)(pA_ + 32 * IN_F);        \
    A##SL##3 = *(const bf16x8*)(pA_ + 48 * IN_F);        \
  } while (0)

#define DQMMA(SL)                                                                      \
  do {                                                                                 \
    bf16x8 bf0 = dqfrag(qa##SL[0], qa##SL[1], qa##SL[2], na##SL);                      \
    bf16x8 bf1 = dqfrag(qb##SL[0], qb##SL[1], qb##SL[2], nb##SL);                      \
    acc[0][0] = __builtin_amdgcn_mfma_f32_16x16x32_bf16(A##SL##0, bf0, acc[0][0], 0, 0, 0); \
    acc[1][0] = __builtin_amdgcn_mfma_f32_16x16x32_bf16(A##SL##0, bf1, acc[1][0], 0, 0, 0); \
    acc[0][1] = __builtin_amdgcn_mfma_f32_16x16x32_bf16(A##SL##1, bf0, acc[0][1], 0, 0, 0); \
    acc[1][1] = __builtin_amdgcn_mfma_f32_16x16x32_bf16(A##SL##1, bf1, acc[1][1], 0, 0, 0); \
    acc[0][2] = __builtin_amdgcn_mfma_f32_16x16x32_bf16(A##SL##2, bf0, acc[0][2], 0, 0, 0); \
    acc[1][2] = __builtin_amdgcn_mfma_f32_16x16x32_bf16(A##SL##2, bf1, acc[1][2], 0, 0, 0); \
    acc[0][3] = __builtin_amdgcn_mfma_f32_16x16x32_bf16(A##SL##3, bf0, acc[0][3], 0, 0, 0); \
    acc[1][3] = __builtin_amdgcn_mfma_f32_16x16x32_bf16(A##SL##3, bf1, acc[1][3], 0, 0, 0); \
  } while (0)

  LOADAB(0, 0);
  LOADAB(1, 1);
  LOADAB(2, 2);
  LOADAB(3, 3);

  int it = 0;
  for (; it < NIT - 4; it += 4) {
    DQMMA(0); LOADAB(0, it + 4);
    DQMMA(1); LOADAB(1, it + 5);
    DQMMA(2); LOADAB(2, it + 6);
    DQMMA(3); LOADAB(3, it + 7);
  }
  DQMMA(0);
  DQMMA(1);
  DQMMA(2);
  DQMMA(3);

#undef LOADAB
#undef DQMMA

  // C/D layout: col = lane&15, row = (lane>>4)*4 + r (verified m89)
  float* pout = partial + (size_t)s * BATCH * OUT_F;
  #pragma unroll
  for (int n = 0; n < 2; ++n) {
    int col = nb + n * 16 + l15;
    #pragma unroll
    for (int m = 0; m < 4; ++m) {
      int rowb = m * 16 + h * 4;
      #pragma unroll
      for (int r = 0; r < 4; ++r)
        pout[(size_t)(rowb + r) * OUT_F + col] = acc[n][m][r];
    }
  }
}

template <int KS>
__global__ void __launch_bounds__(256) reduce_kernel(const float* __restrict__ partial,
                                                     const float* __restrict__ bias,
                                                     float* __restrict__ out) {
  int i = blockIdx.x * 256 + threadIdx.x;
  float4 a = ((const float4*)partial)[i];
  #pragma unroll
  for (int s2 = 1; s2 < KS; ++s2) {
    float4 b = ((const float4*)partial)[i + s2 * (BATCH * OUT_F / 4)];
    a.x += b.x; a.y += b.y; a.z += b.z; a.w += b.w;
  }
  float4 bv = ((const float4*)bias)[i & (OUT_F / 4 - 1)];
  a.x += bv.x; a.y += bv.y; a.z += bv.z; a.w += bv.w;
  ((float4*)out)[i] = a;
}

extern "C" void kernel_launch(void* const* d_in, const int* in_sizes, int n_in,
                              void* d_out, int out_size, void* d_ws, size_t ws_size,
                              hipStream_t stream) {
  const float* x     = (const float*)d_in[0];
  const int*   wq    = (const int*)d_in[1];
  const float* wnorm = (const float*)d_in[2];
  const float* bias  = (const float*)d_in[3];
  float* out = (float*)d_out;

  const size_t xb_bytes = (size_t)BATCH * IN_F * 2;  // 1 MB
  ushort* xb      = (ushort*)d_ws;
  float*  partial = (float*)((char*)d_ws + xb_bytes);

  hipLaunchKernelGGL(xcvt_kernel, dim3(BATCH * IN_F / 4 / 256), dim3(256), 0, stream, x, xb);

  const size_t slice_bytes = (size_t)BATCH * OUT_F * 4;  // 2 MB per k-slice
  if (ws_size >= xb_bytes + 16 * slice_bytes) {
    hipLaunchKernelGGL((gemm3b_kernel<16>), dim3(OUT_F / 128, 16), dim3(256), 0, stream,
                       xb, wq, wnorm, partial);
    hipLaunchKernelGGL((reduce_kernel<16>), dim3(BATCH * OUT_F / 4 / 256), dim3(256), 0, stream,
                       partial, bias, out);
  } else if (ws_size >= xb_bytes + 8 * slice_bytes) {
    hipLaunchKernelGGL((gemm3b_kernel<8>), dim3(OUT_F / 128, 8), dim3(256), 0, stream,
                       xb, wq, wnorm, partial);
    hipLaunchKernelGGL((reduce_kernel<8>), dim3(BATCH * OUT_F / 4 / 256), dim3(256), 0, stream,
                       partial, bias, out);
  } else {
    hipLaunchKernelGGL((gemm3b_kernel<4>), dim3(OUT_F / 128, 4), dim3(256), 0, stream,
                       xb, wq, wnorm, partial);
    hipLaunchKernelGGL((reduce_kernel<4>), dim3(BATCH * OUT_F / 4 / 256), dim3(256), 0, stream,
                       partial, bias, out);
  }
}

// Round 6
// 44.400 us; speedup vs baseline: 1.7575x; 1.7575x over previous
//
#include <hip/hip_runtime.h>
#include <hip/hip_bf16.h>

// LinearMinimumBit: y = x @ dequant3bit(W)^T + bias
// x:[64,8192] f32, weight_q3:[4194304,6] int32 (one byte value per int32),
// weight_norm:[4194304] f32, bias:[8192] f32 -> out:[64,8192] f32
//
// Round 6: m97-style 2-phase pipeline. ALL global traffic is coalesced
// global_load_lds DMA (weights+norms+A staged per 64-k tile, double-buffered,
// one vmcnt(0)+barrier per tile). Rounds 3-5 proved the compiler deletes
// register software-pipelines (VGPR=100 vs ~150 required) and per-lane
// scattered loads congest TCP/L2; the wave-DMA pipeline survives compilation.
//
// ws: [0,1MB) x as bf16; [1MB, 1MB+KS*2MB) partials [KS][64][8192] f32

#define BATCH   64
#define IN_F    8192
#define OUT_F   8192

#define PK_BYTES 12288   // packed weights: 128 rows * 96 B (4 groups * 24 B)
#define PN_BYTES 2048    // norms: 128 rows * 4 f32
#define PA_BYTES 8192    // A tile: 64 rows * 128 B (64 k * bf16), XOR-swizzled
#define BUF_BYTES (PK_BYTES + PN_BYTES + PA_BYTES)  // 22528

typedef __attribute__((ext_vector_type(8))) short bf16x8;
typedef __attribute__((ext_vector_type(4))) float f32x4;

__device__ __forceinline__ ushort f2bf(float f) {
  union { float f; unsigned u; } a; a.f = f;
  unsigned r = a.u + 0x7fffu + ((a.u >> 16) & 1u);
  return (ushort)(r >> 16);
}

__device__ __forceinline__ void gl_lds16(const void* g, void* l) {
  __builtin_amdgcn_global_load_lds((const __attribute__((address_space(1))) void*)g,
                                   (__attribute__((address_space(3))) void*)l, 16, 0, 0);
}
__device__ __forceinline__ void gl_lds4(const void* g, void* l) {
  __builtin_amdgcn_global_load_lds((const __attribute__((address_space(1))) void*)g,
                                   (__attribute__((address_space(3))) void*)l, 4, 0, 0);
}

__global__ void __launch_bounds__(256) xcvt_kernel(const float* __restrict__ x,
                                                   ushort* __restrict__ xb) {
  int i = blockIdx.x * 256 + threadIdx.x;
  float4 v = ((const float4*)x)[i];
  ushort4 o;
  o.x = f2bf(v.x); o.y = f2bf(v.y); o.z = f2bf(v.z); o.w = f2bf(v.w);
  ((ushort4*)xb)[i] = o;
}

// 3 byte-values + norm -> 8 bf16 weights (w = v*(2n/7) - n), k-ascending
__device__ __forceinline__ bf16x8 dqfrag(int b0, int b1, int b2, float nrm) {
  float c1 = nrm * (2.0f / 7.0f);
  float c0 = nrm;
  int v0 = (b0 >> 5) & 7;
  int v1 = (b0 >> 2) & 7;
  int v2 = ((b0 & 3) << 1) | ((b1 >> 7) & 1);
  int v3 = (b1 >> 4) & 7;
  int v4 = (b1 >> 1) & 7;
  int v5 = ((b1 & 1) << 2) | ((b2 >> 6) & 3);
  int v6 = (b2 >> 3) & 7;
  int v7 = b2 & 7;
  union { __hip_bfloat162 h[4]; bf16x8 v; } r;
  r.h[0] = __float22bfloat162_rn(make_float2(fmaf((float)v0, c1, -c0), fmaf((float)v1, c1, -c0)));
  r.h[1] = __float22bfloat162_rn(make_float2(fmaf((float)v2, c1, -c0), fmaf((float)v3, c1, -c0)));
  r.h[2] = __float22bfloat162_rn(make_float2(fmaf((float)v4, c1, -c0), fmaf((float)v5, c1, -c0)));
  r.h[3] = __float22bfloat162_rn(make_float2(fmaf((float)v6, c1, -c0), fmaf((float)v7, c1, -c0)));
  return r.v;
}

template <int KS>
__global__ void __launch_bounds__(256) gemm3b_kernel(const ushort* __restrict__ xb,
                                                     const int* __restrict__ wq,
                                                     const float* __restrict__ wnorm,
                                                     float* __restrict__ partial) {
  constexpr int K_SLICE = IN_F / KS;
  constexpr int NTILE = K_SLICE / 64;   // 64-k per staged tile (even: 16 @KS=8, 32 @KS=4)

  __shared__ __align__(16) char LDS[2][BUF_BYTES];

  const int tid  = threadIdx.x;
  const int lane = tid & 63;
  const int w    = tid >> 6;          // wave w owns cols [nb128 + w*32, +32)
  const int l15  = lane & 15;
  const int h    = lane >> 4;         // k-chunk within 32-k
  const int nb128 = blockIdx.x * 128;
  const int s    = blockIdx.y;
  const int kbase = s * K_SLICE;
  const int kg0   = kbase >> 4;       // group offset along a row

  // stage source bases (block-uniform except per-lane offsets below)
  const char*  wqp = (const char*)wq + (size_t)nb128 * 12288 + (size_t)kg0 * 24;
  const float* wnp = wnorm + (size_t)nb128 * 512 + kg0;
  const char*  xbp = (const char*)xb + (size_t)kbase * 2;

  f32x4 acc[2][4];
  #pragma unroll
  for (int n = 0; n < 2; ++n)
    #pragma unroll
    for (int m = 0; m < 4; ++m) acc[n][m] = (f32x4){0.f, 0.f, 0.f, 0.f};

#define STAGE(BUF, KT)                                                        \
  do {                                                                        \
    /* packed weights: 12288 B, 3 x 16B-DMA; row = t/96 via magic mul */      \
    _Pragma("unroll")                                                         \
    for (int i = 0; i < 3; ++i) {                                             \
      int t = tid * 16 + i * 4096;                                            \
      int row = (int)(((unsigned)t * 43691u) >> 22);                          \
      int off = t - row * 96;                                                 \
      gl_lds16(wqp + (size_t)row * 12288 + (KT) * 96 + off,                   \
               &LDS[BUF][i * 4096 + w * 1024]);                               \
    }                                                                         \
    /* norms: 2048 B, 2 x 4B-DMA */                                           \
    _Pragma("unroll")                                                         \
    for (int i = 0; i < 2; ++i) {                                             \
      int t2 = tid * 4 + i * 1024;                                            \
      int row = t2 >> 4;                                                      \
      int g = (t2 >> 2) & 3;                                                  \
      gl_lds4(wnp + (size_t)row * 512 + (KT) * 4 + g,                         \
              &LDS[BUF][PK_BYTES + i * 1024 + w * 256]);                      \
    }                                                                         \
    /* A tile: 8192 B, 2 x 16B-DMA; XOR-swizzled source (rule #21) */         \
    _Pragma("unroll")                                                         \
    for (int i = 0; i < 2; ++i) {                                             \
      int t = tid * 16 + i * 4096;                                            \
      int row = t >> 7;                                                       \
      int s16 = (t >> 4) & 7;                                                 \
      int c16 = s16 ^ (row & 7);                                              \
      gl_lds16(xbp + (size_t)row * (IN_F * 2) + (KT) * 128 + c16 * 16,        \
               &LDS[BUF][PK_BYTES + PN_BYTES + i * 4096 + w * 1024]);         \
    }                                                                         \
  } while (0)

#define COMPUTE(BUF)                                                          \
  do {                                                                        \
    const char*  pk  = &LDS[BUF][0];                                          \
    const float* pnf = (const float*)&LDS[BUF][PK_BYTES];                     \
    const char*  pa  = &LDS[BUF][PK_BYTES + PN_BYTES];                        \
    _Pragma("unroll")                                                         \
    for (int ks = 0; ks < 2; ++ks) {                                          \
      bf16x8 af[4];                                                           \
      _Pragma("unroll")                                                       \
      for (int m = 0; m < 4; ++m) {                                           \
        int row = m * 16 + l15;                                               \
        int cch = ks * 4 + h;                                                 \
        af[m] = *(const bf16x8*)(pa + row * 128 + ((cch ^ (row & 7)) * 16));  \
      }                                                                       \
      bf16x8 bfr[2];                                                          \
      _Pragma("unroll")                                                       \
      for (int n = 0; n < 2; ++n) {                                           \
        int r = w * 32 + n * 16 + l15;                                        \
        int g = ks * 2 + (h >> 1);                                            \
        const uint* p = (const uint*)(pk + r * 96 + g * 24 + (h & 1) * 12);   \
        bfr[n] = dqfrag(p[0], p[1], p[2], pnf[r * 4 + g]);                    \
      }                                                                       \
      _Pragma("unroll")                                                       \
      for (int m = 0; m < 4; ++m)                                             \
        _Pragma("unroll")                                                     \
        for (int n = 0; n < 2; ++n)                                           \
          acc[n][m] = __builtin_amdgcn_mfma_f32_16x16x32_bf16(af[m], bfr[n],  \
                                                              acc[n][m], 0, 0, 0); \
    }                                                                         \
  } while (0)

  STAGE(0, 0);
  __syncthreads();                 // drains DMA (vmcnt) + lgkm

  for (int kt = 0; kt < NTILE; kt += 2) {
    if (kt + 1 < NTILE) STAGE(1, kt + 1);   // issue next-tile DMA BEFORE compute
    COMPUTE(0);
    __syncthreads();
    if (kt + 2 < NTILE) STAGE(0, kt + 2);
    COMPUTE(1);
    __syncthreads();
  }

#undef STAGE
#undef COMPUTE

  // C/D layout: col = lane&15, row = (lane>>4)*4 + r (verified m89)
  float* pout = partial + (size_t)s * BATCH * OUT_F;
  const int nb = nb128 + w * 32;
  #pragma unroll
  for (int n = 0; n < 2; ++n) {
    int col = nb + n * 16 + l15;
    #pragma unroll
    for (int m = 0; m < 4; ++m) {
      int rowb = m * 16 + h * 4;
      #pragma unroll
      for (int r = 0; r < 4; ++r)
        pout[(size_t)(rowb + r) * OUT_F + col] = acc[n][m][r];
    }
  }
}

template <int KS>
__global__ void __launch_bounds__(256) reduce_kernel(const float* __restrict__ partial,
                                                     const float* __restrict__ bias,
                                                     float* __restrict__ out) {
  int i = blockIdx.x * 256 + threadIdx.x;
  float4 a = ((const float4*)partial)[i];
  #pragma unroll
  for (int s2 = 1; s2 < KS; ++s2) {
    float4 b = ((const float4*)partial)[i + s2 * (BATCH * OUT_F / 4)];
    a.x += b.x; a.y += b.y; a.z += b.z; a.w += b.w;
  }
  float4 bv = ((const float4*)bias)[i & (OUT_F / 4 - 1)];
  a.x += bv.x; a.y += bv.y; a.z += bv.z; a.w += bv.w;
  ((float4*)out)[i] = a;
}

extern "C" void kernel_launch(void* const* d_in, const int* in_sizes, int n_in,
                              void* d_out, int out_size, void* d_ws, size_t ws_size,
                              hipStream_t stream) {
  const float* x     = (const float*)d_in[0];
  const int*   wq    = (const int*)d_in[1];
  const float* wnorm = (const float*)d_in[2];
  const float* bias  = (const float*)d_in[3];
  float* out = (float*)d_out;

  const size_t xb_bytes = (size_t)BATCH * IN_F * 2;  // 1 MB
  ushort* xb      = (ushort*)d_ws;
  float*  partial = (float*)((char*)d_ws + xb_bytes);

  hipLaunchKernelGGL(xcvt_kernel, dim3(BATCH * IN_F / 4 / 256), dim3(256), 0, stream, x, xb);

  const size_t slice_bytes = (size_t)BATCH * OUT_F * 4;  // 2 MB per k-slice
  if (ws_size >= xb_bytes + 8 * slice_bytes) {
    hipLaunchKernelGGL((gemm3b_kernel<8>), dim3(OUT_F / 128, 8), dim3(256), 0, stream,
                       xb, wq, wnorm, partial);
    hipLaunchKernelGGL((reduce_kernel<8>), dim3(BATCH * OUT_F / 4 / 256), dim3(256), 0, stream,
                       partial, bias, out);
  } else {
    hipLaunchKernelGGL((gemm3b_kernel<4>), dim3(OUT_F / 128, 4), dim3(256), 0, stream,
                       xb, wq, wnorm, partial);
    hipLaunchKernelGGL((reduce_kernel<4>), dim3(BATCH * OUT_F / 4 / 256), dim3(256), 0, stream,
                       partial, bias, out);
  }
}

// Round 7
// 42.841 us; speedup vs baseline: 1.8215x; 1.0364x over previous
//
#include <hip/hip_runtime.h>
#include <hip/hip_bf16.h>

// LinearMinimumBit: y = x @ dequant3bit(W)^T + bias
// x:[64,8192] f32, weight_q3:[4194304,6] int32 (one byte value per int32),
// weight_norm:[4194304] f32, bias:[8192] f32 -> out:[64,8192] f32
//
// Round 7: T3+T4 counted-vmcnt pipeline. 3 LDS buffers, STAGE issued 2 tiles
// ahead, raw s_barrier + s_waitcnt vmcnt(7) (exactly 7 global_load_lds per
// thread per tile -> FIFO arithmetic exact; never drain vmcnt to 0 in-loop).
// Round 6's __syncthreads() drained vmcnt every tile = the m233 2-phase stall.
//
// ws: [0,1MB) x as bf16; [1MB, 1MB+KS*2MB) partials [KS][64][8192] f32

#define BATCH   64
#define IN_F    8192
#define OUT_F   8192

#define PK_BYTES 12288   // packed weights: 128 rows * 96 B (4 groups * 24 B)
#define PN_BYTES 2048    // norms: 128 rows * 4 f32
#define PA_BYTES 8192    // A tile: 64 rows * 128 B (64 k * bf16), XOR-swizzled
#define BUF_BYTES (PK_BYTES + PN_BYTES + PA_BYTES)  // 22528

typedef __attribute__((ext_vector_type(8))) short bf16x8;
typedef __attribute__((ext_vector_type(4))) float f32x4;

__device__ __forceinline__ ushort f2bf(float f) {
  union { float f; unsigned u; } a; a.f = f;
  unsigned r = a.u + 0x7fffu + ((a.u >> 16) & 1u);
  return (ushort)(r >> 16);
}

__device__ __forceinline__ void gl_lds16(const void* g, void* l) {
  __builtin_amdgcn_global_load_lds((const __attribute__((address_space(1))) void*)g,
                                   (__attribute__((address_space(3))) void*)l, 16, 0, 0);
}
__device__ __forceinline__ void gl_lds4(const void* g, void* l) {
  __builtin_amdgcn_global_load_lds((const __attribute__((address_space(1))) void*)g,
                                   (__attribute__((address_space(3))) void*)l, 4, 0, 0);
}

__global__ void __launch_bounds__(256) xcvt_kernel(const float* __restrict__ x,
                                                   ushort* __restrict__ xb) {
  int i = blockIdx.x * 256 + threadIdx.x;
  float4 v = ((const float4*)x)[i];
  ushort4 o;
  o.x = f2bf(v.x); o.y = f2bf(v.y); o.z = f2bf(v.z); o.w = f2bf(v.w);
  ((ushort4*)xb)[i] = o;
}

// 3 byte-values + norm -> 8 bf16 weights (w = v*(2n/7) - n), k-ascending
__device__ __forceinline__ bf16x8 dqfrag(int b0, int b1, int b2, float nrm) {
  float c1 = nrm * (2.0f / 7.0f);
  float c0 = nrm;
  int v0 = (b0 >> 5) & 7;
  int v1 = (b0 >> 2) & 7;
  int v2 = ((b0 & 3) << 1) | ((b1 >> 7) & 1);
  int v3 = (b1 >> 4) & 7;
  int v4 = (b1 >> 1) & 7;
  int v5 = ((b1 & 1) << 2) | ((b2 >> 6) & 3);
  int v6 = (b2 >> 3) & 7;
  int v7 = b2 & 7;
  union { __hip_bfloat162 h[4]; bf16x8 v; } r;
  r.h[0] = __float22bfloat162_rn(make_float2(fmaf((float)v0, c1, -c0), fmaf((float)v1, c1, -c0)));
  r.h[1] = __float22bfloat162_rn(make_float2(fmaf((float)v2, c1, -c0), fmaf((float)v3, c1, -c0)));
  r.h[2] = __float22bfloat162_rn(make_float2(fmaf((float)v4, c1, -c0), fmaf((float)v5, c1, -c0)));
  r.h[3] = __float22bfloat162_rn(make_float2(fmaf((float)v6, c1, -c0), fmaf((float)v7, c1, -c0)));
  return r.v;
}

template <int KS>
__global__ void __launch_bounds__(256) gemm3b_kernel(const ushort* __restrict__ xb,
                                                     const int* __restrict__ wq,
                                                     const float* __restrict__ wnorm,
                                                     float* __restrict__ partial) {
  constexpr int K_SLICE = IN_F / KS;
  constexpr int NTILE = K_SLICE / 64;   // 64-k per staged tile (16 @KS=8)

  __shared__ __align__(16) char LDS[3][BUF_BYTES];

  const int tid  = threadIdx.x;
  const int lane = tid & 63;
  const int w    = tid >> 6;          // wave w owns cols [nb128 + w*32, +32)
  const int l15  = lane & 15;
  const int h    = lane >> 4;         // k-chunk within 32-k
  const int nb128 = blockIdx.x * 128;
  const int s    = blockIdx.y;
  const int kbase = s * K_SLICE;
  const int kg0   = kbase >> 4;       // group offset along a row

  const char*  wqp = (const char*)wq + (size_t)nb128 * 12288 + (size_t)kg0 * 24;
  const float* wnp = wnorm + (size_t)nb128 * 512 + kg0;
  const char*  xbp = (const char*)xb + (size_t)kbase * 2;

  f32x4 acc[2][4];
  #pragma unroll
  for (int n = 0; n < 2; ++n)
    #pragma unroll
    for (int m = 0; m < 4; ++m) acc[n][m] = (f32x4){0.f, 0.f, 0.f, 0.f};

  // STAGE = exactly 7 global_load_lds per thread (3 pk + 2 pn + 2 pa):
  // vmcnt arithmetic below depends on this count.
#define STAGE(BUF, KT)                                                        \
  do {                                                                        \
    _Pragma("unroll")                                                         \
    for (int i = 0; i < 3; ++i) {                                             \
      int t = tid * 16 + i * 4096;                                            \
      int row = (int)(((unsigned)t * 43691u) >> 22);                          \
      int off = t - row * 96;                                                 \
      gl_lds16(wqp + (size_t)row * 12288 + (KT) * 96 + off,                   \
               &LDS[BUF][i * 4096 + w * 1024]);                               \
    }                                                                         \
    _Pragma("unroll")                                                         \
    for (int i = 0; i < 2; ++i) {                                             \
      int t2 = tid * 4 + i * 1024;                                            \
      int row = t2 >> 4;                                                      \
      int g = (t2 >> 2) & 3;                                                  \
      gl_lds4(wnp + (size_t)row * 512 + (KT) * 4 + g,                         \
              &LDS[BUF][PK_BYTES + i * 1024 + w * 256]);                      \
    }                                                                         \
    _Pragma("unroll")                                                         \
    for (int i = 0; i < 2; ++i) {                                             \
      int t = tid * 16 + i * 4096;                                            \
      int row = t >> 7;                                                       \
      int s16 = (t >> 4) & 7;                                                 \
      int c16 = s16 ^ (row & 7);                                              \
      gl_lds16(xbp + (size_t)row * (IN_F * 2) + (KT) * 128 + c16 * 16,        \
               &LDS[BUF][PK_BYTES + PN_BYTES + i * 4096 + w * 1024]);         \
    }                                                                         \
  } while (0)

#define COMPUTE(BUF)                                                          \
  do {                                                                        \
    const char*  pk  = &LDS[BUF][0];                                          \
    const float* pnf = (const float*)&LDS[BUF][PK_BYTES];                     \
    const char*  pa  = &LDS[BUF][PK_BYTES + PN_BYTES];                        \
    _Pragma("unroll")                                                         \
    for (int ks = 0; ks < 2; ++ks) {                                          \
      bf16x8 af[4];                                                           \
      _Pragma("unroll")                                                       \
      for (int m = 0; m < 4; ++m) {                                           \
        int row = m * 16 + l15;                                               \
        int cch = ks * 4 + h;                                                 \
        af[m] = *(const bf16x8*)(pa + row * 128 + ((cch ^ (row & 7)) * 16));  \
      }                                                                       \
      bf16x8 bfr[2];                                                          \
      _Pragma("unroll")                                                       \
      for (int n = 0; n < 2; ++n) {                                           \
        int r = w * 32 + n * 16 + l15;                                        \
        int g = ks * 2 + (h >> 1);                                            \
        const uint* p = (const uint*)(pk + r * 96 + g * 24 + (h & 1) * 12);   \
        bfr[n] = dqfrag(p[0], p[1], p[2], pnf[r * 4 + g]);                    \
      }                                                                       \
      _Pragma("unroll")                                                       \
      for (int m = 0; m < 4; ++m)                                             \
        _Pragma("unroll")                                                     \
        for (int n = 0; n < 2; ++n)                                           \
          acc[n][m] = __builtin_amdgcn_mfma_f32_16x16x32_bf16(af[m], bfr[n],  \
                                                              acc[n][m], 0, 0, 0); \
    }                                                                         \
  } while (0)

  STAGE(0, 0);
  STAGE(1, 1);

  // steady state: stages kt, kt+1 in flight (14 loads) at the wait point;
  // vmcnt(7) retires exactly stage kt (issued 2 phases ago). Never 0 in-loop.
  #pragma unroll
  for (int kt = 0; kt < NTILE - 1; ++kt) {
    asm volatile("s_waitcnt vmcnt(7)" ::: "memory");
    __builtin_amdgcn_s_barrier();
    asm volatile("" ::: "memory");   // fence: keep ds_reads below the barrier
    if (kt + 2 < NTILE) STAGE((kt + 2) % 3, kt + 2);
    COMPUTE(kt % 3);
  }
  asm volatile("s_waitcnt vmcnt(0)" ::: "memory");
  __builtin_amdgcn_s_barrier();
  asm volatile("" ::: "memory");
  COMPUTE((NTILE - 1) % 3);

#undef STAGE
#undef COMPUTE

  // C/D layout: col = lane&15, row = (lane>>4)*4 + r (verified m89)
  float* pout = partial + (size_t)s * BATCH * OUT_F;
  const int nb = nb128 + w * 32;
  #pragma unroll
  for (int n = 0; n < 2; ++n) {
    int col = nb + n * 16 + l15;
    #pragma unroll
    for (int m = 0; m < 4; ++m) {
      int rowb = m * 16 + h * 4;
      #pragma unroll
      for (int r = 0; r < 4; ++r)
        pout[(size_t)(rowb + r) * OUT_F + col] = acc[n][m][r];
    }
  }
}

template <int KS>
__global__ void __launch_bounds__(256) reduce_kernel(const float* __restrict__ partial,
                                                     const float* __restrict__ bias,
                                                     float* __restrict__ out) {
  int i = blockIdx.x * 256 + threadIdx.x;
  float4 a = ((const float4*)partial)[i];
  #pragma unroll
  for (int s2 = 1; s2 < KS; ++s2) {
    float4 b = ((const float4*)partial)[i + s2 * (BATCH * OUT_F / 4)];
    a.x += b.x; a.y += b.y; a.z += b.z; a.w += b.w;
  }
  float4 bv = ((const float4*)bias)[i & (OUT_F / 4 - 1)];
  a.x += bv.x; a.y += bv.y; a.z += bv.z; a.w += bv.w;
  ((float4*)out)[i] = a;
}

extern "C" void kernel_launch(void* const* d_in, const int* in_sizes, int n_in,
                              void* d_out, int out_size, void* d_ws, size_t ws_size,
                              hipStream_t stream) {
  const float* x     = (const float*)d_in[0];
  const int*   wq    = (const int*)d_in[1];
  const float* wnorm = (const float*)d_in[2];
  const float* bias  = (const float*)d_in[3];
  float* out = (float*)d_out;

  const size_t xb_bytes = (size_t)BATCH * IN_F * 2;  // 1 MB
  ushort* xb      = (ushort*)d_ws;
  float*  partial = (float*)((char*)d_ws + xb_bytes);

  hipLaunchKernelGGL(xcvt_kernel, dim3(BATCH * IN_F / 4 / 256), dim3(256), 0, stream, x, xb);

  const size_t slice_bytes = (size_t)BATCH * OUT_F * 4;  // 2 MB per k-slice
  if (ws_size >= xb_bytes + 8 * slice_bytes) {
    hipLaunchKernelGGL((gemm3b_kernel<8>), dim3(OUT_F / 128, 8), dim3(256), 0, stream,
                       xb, wq, wnorm, partial);
    hipLaunchKernelGGL((reduce_kernel<8>), dim3(BATCH * OUT_F / 4 / 256), dim3(256), 0, stream,
                       partial, bias, out);
  } else {
    hipLaunchKernelGGL((gemm3b_kernel<4>), dim3(OUT_F / 128, 4), dim3(256), 0, stream,
                       xb, wq, wnorm, partial);
    hipLaunchKernelGGL((reduce_kernel<4>), dim3(BATCH * OUT_F / 4 / 256), dim3(256), 0, stream,
                       partial, bias, out);
  }
}